// Round 17
// baseline (188.960 us; speedup 1.0000x reference)
//
#include <hip/hip_runtime.h>

// ---------------------------------------------------------------------------
// unit_gcn: out[n,o,t,v] = BN+ReLU of  sum_{s=0..24} Ws[s] @_c x[n,:,t,(v+s)%25]
//   Ws[0] = sum_i W[i,:,:,0];  Ws[s] = W[s-1,:,:,1]  (s>=1); bias cancels in BN.
// N=64, C=64, T=300, V=25, O=64.  x fp32 -> bf16 MFMA, fp32 accum.
// v14 (R17): 32x32x16 MFMA — halves K-loop instruction count (16 MFMA + 16
// ds_read per shift), same R13/R16 shell: B 2x8KB LDS dbuf, 1 barrier/shift,
// A_T slab (slot = 8-c group -> all k-offsets are immediates). C/D mapping:
// col=lane&31, row=(reg&3)+8*(reg>>2)+4*(lane>>5) [guide-verified].
// ---------------------------------------------------------------------------

typedef short  s16x8  __attribute__((ext_vector_type(8)));
typedef float  f32x4  __attribute__((ext_vector_type(4)));
typedef float  f32x16 __attribute__((ext_vector_type(16)));

#define NTHR_   256
#define RPB_    250         // rows per block (exactly 10 t x 25 v)
#define NBR_    30          // 7500 / 250
#define TS_     252         // epilogue transpose stride (f32); 252*4=63*16B

__device__ __forceinline__ unsigned short f2bf(float f) {
  unsigned u = __builtin_bit_cast(unsigned, f);
  return (unsigned short)((u + 0x7FFFu + ((u >> 16) & 1u)) >> 16);
}

// --- P0: pack Ws into 32x32x16 MFMA B-fragment layout ----------------------
// Wg entry idx = ((s*4 + ks)*2 + ct)*64 + lane ; 8 bf16 per entry:
//   elem j = Ws[s][ o = ct*32 + (lane&31) ][ k = ks*16 + (lane>>5)*8 + j ]
__global__ void pack_w_kernel(const float* __restrict__ W, s16x8* __restrict__ Wg) {
  int idx = blockIdx.x * 256 + threadIdx.x;
  if (idx >= 12800) return;
  int lane = idx & 63;
  int rest = idx >> 6;          // s*8 + ks*2 + ct
  int ct   = rest & 1;
  int ks   = (rest >> 1) & 3;
  int s    = rest >> 3;
  int o    = (ct << 5) + (lane & 31);
  int kb   = (ks << 4) + ((lane >> 5) << 3);
  s16x8 h;
#pragma unroll
  for (int j = 0; j < 8; ++j) {
    int k = kb + j;
    float val;
    if (s == 0) {
      val = 0.f;
      for (int i = 0; i < 24; ++i) val += W[((i * 64 + o) * 64 + k) * 2];
    } else {
      val = W[(((s - 1) * 64 + o) * 64 + k) * 2 + 1];
    }
    h[j] = (short)f2bf(val);
  }
  Wg[idx] = h;
}

// advance row-tile J's shift state (period 25); aoc is byte offset into Ash
#define ADV(J) { bool w_ = (u[J] == 24); u[J] = w_ ? 0 : u[J] + 1; \
                 aoc[J] += w_ ? -384 : 16; }
// one 32x32x16 MFMA
#define MM32(RT, CT, AF, BF) \
  acc[RT][CT] = __builtin_amdgcn_mfma_f32_32x32x16_bf16(AF, BF, acc[RT][CT], 0, 0, 0);

// One shift s (buffer BB = s&1). Entry: Q-set = frags of ks0,1 of s.
// PH_A: 8 MFMA (ks0,1) + read R-set (ks2,3; A at +16384/+24576, B Bsh[BB]+4K).
// barrier. PH_B: 8 MFMA (ks2,3) + ADV + read Q-set (s+1 ks0,1; B Bsh[BB^1]).
// Then write B(s+2) (reg-staged at shift top) into Bsh[BB].
#define SHIFT32(S_, BB)                                                        \
  {                                                                            \
    int sc_ = (S_) + 2; sc_ = (sc_ > 24) ? 24 : sc_;                           \
    const s16x8* ws_ = Wg + sc_ * 512;                                         \
    s16x8 Br0_ = ws_[tid], Br1_ = ws_[256 + tid];                              \
    const char* bq_ = Bsh + (BB) * 8192 + 4096 + (lane << 4);                  \
    __builtin_amdgcn_s_setprio(1);                                             \
    Ra00 = *(const s16x8*)(Ash + aoc[0] + 16384);                              \
    MM32(0, 0, Qa00, Qb00)                                                     \
    Ra10 = *(const s16x8*)(Ash + aoc[1] + 16384);                              \
    MM32(1, 0, Qa10, Qb00)                                                     \
    Ra01 = *(const s16x8*)(Ash + aoc[0] + 24576);                              \
    MM32(0, 1, Qa00, Qb01)                                                     \
    Ra11 = *(const s16x8*)(Ash + aoc[1] + 24576);                              \
    MM32(1, 1, Qa10, Qb01)                                                     \
    Rb00 = *(const s16x8*)(bq_);                                               \
    MM32(0, 0, Qa01, Qb10)                                                     \
    Rb01 = *(const s16x8*)(bq_ + 1024);                                        \
    MM32(0, 1, Qa01, Qb11)                                                     \
    Rb10 = *(const s16x8*)(bq_ + 2048);                                        \
    MM32(1, 0, Qa11, Qb10)                                                     \
    Rb11 = *(const s16x8*)(bq_ + 3072);                                        \
    MM32(1, 1, Qa11, Qb11)                                                     \
    __builtin_amdgcn_s_setprio(0);                                             \
    __syncthreads();                                                           \
    const char* bp_ = Bsh + (((BB) ^ 1) * 8192) + (lane << 4);                 \
    __builtin_amdgcn_s_setprio(1);                                             \
    ADV(0)                                                                     \
    Qa00 = *(const s16x8*)(Ash + aoc[0]);                                      \
    MM32(0, 0, Ra00, Rb00)                                                     \
    ADV(1)                                                                     \
    Qa10 = *(const s16x8*)(Ash + aoc[1]);                                      \
    MM32(1, 0, Ra10, Rb00)                                                     \
    Qa01 = *(const s16x8*)(Ash + aoc[0] + 8192);                               \
    MM32(0, 1, Ra00, Rb01)                                                     \
    Qa11 = *(const s16x8*)(Ash + aoc[1] + 8192);                               \
    MM32(1, 1, Ra10, Rb01)                                                     \
    Qb00 = *(const s16x8*)(bp_);                                               \
    MM32(0, 0, Ra01, Rb10)                                                     \
    Qb01 = *(const s16x8*)(bp_ + 1024);                                        \
    MM32(0, 1, Ra01, Rb11)                                                     \
    Qb10 = *(const s16x8*)(bp_ + 2048);                                        \
    MM32(1, 0, Ra11, Rb10)                                                     \
    Qb11 = *(const s16x8*)(bp_ + 3072);                                        \
    MM32(1, 1, Ra11, Rb11)                                                     \
    __builtin_amdgcn_s_setprio(0);                                             \
    *(s16x8*)(Bsh + (BB) * 8192 + (tid << 4)) = Br0_;                          \
    *(s16x8*)(Bsh + (BB) * 8192 + 4096 + (tid << 4)) = Br1_;                   \
  }

// --- P1: main tap-GEMM -----------------------------------------------------
// grid (br=30, n=64), 256 thr = 4 waves; wave owns 64 rows x 64 o as
// 2x2 tiles of 32x32, K=64 as 4 slices of 16. A_T[slot 0..7][row 0..255]
// 16B frags; frag(row, ks) addr = (ks*2 + (lane>>5))*4096 + row*16.
// LDS = Ash 32K + Bsh 16K = 48K; red2 aliases Bsh (dead post-K-loop).
__global__ __launch_bounds__(NTHR_) void tap_mm_kernel(
    const float* __restrict__ x, const s16x8* __restrict__ Wg,
    float* __restrict__ out, float* __restrict__ partials) {
  __shared__ __align__(16) char Ash[32768];   // A_T 8x256x16B; epi T[32][252]
  __shared__ __align__(16) char Bsh[16384];   // B dbuf 2x8KB; later red2[512]
  float* red2 = (float*)Bsh;
  int br = blockIdx.x, n = blockIdx.y;
  int r0 = br * RPB_;                 // 25-aligned
  const float* xn = x + n * 480000 + r0;
  int tid = threadIdx.x;
  int wid = tid >> 6, lane = tid & 63;
  int l31 = lane & 31, hi = lane >> 5;

  // ---- B prologue: shifts 0 and 1 -> regs (L2-hot)
  s16x8 p0 = Wg[tid], p1 = Wg[256 + tid], p2 = Wg[512 + tid], p3 = Wg[768 + tid];

  // ---- stage A_T: iteration it = slot (8-c group); row = tid (250..255 pad)
#pragma unroll 2
  for (int it = 0; it < 8; ++it) {
    bool vld = tid < RPB_;
    s16x8 h;
#pragma unroll
    for (int j = 0; j < 8; ++j) {
      float f = vld ? xn[((it << 3) + j) * 7500 + tid] : 0.f;
      h[j] = (short)f2bf(f);
    }
    *(s16x8*)(Ash + (it << 12) + (tid << 4)) = h;
  }
  // B(0) -> Bsh[0], B(1) -> Bsh[1]
  *(s16x8*)(Bsh + (tid << 4))         = p0;
  *(s16x8*)(Bsh + 4096 + (tid << 4))  = p1;
  *(s16x8*)(Bsh + 8192 + (tid << 4))  = p2;
  *(s16x8*)(Bsh + 12288 + (tid << 4)) = p3;

  // ---- per-lane A row state: aoc = hi*4096 + srow*16 (ks0 byte offset)
  int u[2], aoc[2];
#pragma unroll
  for (int rt = 0; rt < 2; ++rt) {
    int srow = (wid << 6) + (rt << 5) + l31;     // local slab row (A-side)
    u[rt]   = srow % 25;                         // r0 is 25-aligned
    aoc[rt] = (hi << 12) + (srow << 4);
  }
  f32x16 acc[2][2];
#pragma unroll
  for (int rt = 0; rt < 2; ++rt)
#pragma unroll
    for (int ct = 0; ct < 2; ++ct) acc[rt][ct] = (f32x16)(0.f);

  __syncthreads();

  // ---- preload Q-set: shift 0, ks0 (aoc) and ks1 (+8192); B from Bsh[0]
  s16x8 Qa00 = *(const s16x8*)(Ash + aoc[0]);
  s16x8 Qa10 = *(const s16x8*)(Ash + aoc[1]);
  s16x8 Qa01 = *(const s16x8*)(Ash + aoc[0] + 8192);
  s16x8 Qa11 = *(const s16x8*)(Ash + aoc[1] + 8192);
  const char* b0_ = Bsh + (lane << 4);
  s16x8 Qb00 = *(const s16x8*)(b0_);
  s16x8 Qb01 = *(const s16x8*)(b0_ + 1024);
  s16x8 Qb10 = *(const s16x8*)(b0_ + 2048);
  s16x8 Qb11 = *(const s16x8*)(b0_ + 3072);
  s16x8 Ra00, Ra10, Ra01, Ra11, Rb00, Rb01, Rb10, Rb11;

  // ---- 25 shifts (buffer parity = s&1)
  for (int k = 0; k < 12; ++k) {
    SHIFT32(2 * k, 0)
    SHIFT32(2 * k + 1, 1)
  }
  SHIFT32(24, 0)

  __syncthreads();   // all waves done with Ash/Bsh -> safe to alias red2

  // ---- per-channel sum/sumsq from registers (rows < 250 only)
  // C/D: o = ct*32 + l31 (fixed per lane!), row = (r&3) + 8*(r>>2) + 4*hi
  float s1v[2] = {0.f, 0.f}, s2v[2] = {0.f, 0.f};
#pragma unroll
  for (int rt = 0; rt < 2; ++rt)
#pragma unroll
    for (int r = 0; r < 16; ++r) {
      int row = (wid << 6) + (rt << 5) + (r & 3) + ((r >> 2) << 3) + (hi << 2);
      if (row < RPB_) {
        float v0 = acc[rt][0][r], v1 = acc[rt][1][r];
        s1v[0] += v0; s2v[0] += v0 * v0;
        s1v[1] += v1; s2v[1] += v1 * v1;
      }
    }
#pragma unroll
  for (int ct = 0; ct < 2; ++ct) {
    float a = s1v[ct], b = s2v[ct];
    a += __shfl_xor(a, 32); b += __shfl_xor(b, 32);
    if (lane < 32) {
      int base = ((((wid << 1) + ct) << 5) + l31) * 2;
      red2[base]     = a;
      red2[base + 1] = b;
    }
  }

  // ---- epilogue: 2 o-halves (ct) via LDS transpose, coalesced f2 stores
  float* T = (float*)Ash;
  float* outb = out + n * 480000 + r0;     // + o*7500 + row
#pragma unroll
  for (int ct = 0; ct < 2; ++ct) {
    __syncthreads();   // ct0: K-loop Ash reads + red2 writes done; else T reads
    // write acc[.][ct] -> T[o_local][row]; reg quad 4q..4q+3 = 4 contiguous rows
#pragma unroll
    for (int rt = 0; rt < 2; ++rt)
#pragma unroll
      for (int q = 0; q < 4; ++q) {
        int trow = (wid << 6) + (rt << 5) + (q << 3) + (hi << 2);
        if (trow < RPB_) {
          f32x4 v = {acc[rt][ct][4 * q],     acc[rt][ct][4 * q + 1],
                     acc[rt][ct][4 * q + 2], acc[rt][ct][4 * q + 3]};
          *(f32x4*)&T[l31 * TS_ + trow] = v;
        }
      }
    __syncthreads();
    if (ct == 0 && tid < 128) {   // deterministic partial reduction
      int o = tid >> 1, m = tid & 1;
      float sres = 0.f;
#pragma unroll
      for (int w = 0; w < 4; ++w)
        sres += red2[((((w << 1) + (o >> 5)) << 5) + (o & 31)) * 2 + m];
      int bl = n * NBR_ + br;
      partials[bl * 128 + m * 64 + o] = sres;
    }
    // stores: 32 o x 125 float2 rows (250 rows, 8B aligned for any br)
#pragma unroll 4
    for (int it = 0; it < 16; ++it) {
      int idx = tid + it * NTHR_;
      if (idx < 4000) {
        int ol = idx / 125, r2 = idx - ol * 125;
        *(float2*)&outb[((ct << 5) + ol) * 7500 + (r2 << 1)] =
            *(float2*)&T[ol * TS_ + (r2 << 1)];
      }
    }
  }
}

// --- P2: reduce per-block partials -> per-channel scale/shift --------------
__global__ void finalize_kernel(const float* __restrict__ part,
                                const float* __restrict__ gamma,
                                const float* __restrict__ beta,
                                float* __restrict__ scsh) {
  __shared__ float sm[512];
  int o = blockIdx.x;            // 64 blocks, one channel each
  int tid = threadIdx.x;         // 256 threads
  float s1 = 0.f, s2 = 0.f;
  for (int b = tid; b < 64 * NBR_; b += 256) {
    s1 += part[b * 128 + o];
    s2 += part[b * 128 + 64 + o];
  }
  sm[tid] = s1; sm[256 + tid] = s2;
  __syncthreads();
  for (int st = 128; st >= 1; st >>= 1) {
    if (tid < st) { sm[tid] += sm[tid + st]; sm[256 + tid] += sm[256 + tid + st]; }
    __syncthreads();
  }
  if (tid == 0) {
    const float inv = 1.0f / 480000.0f;
    float mean = sm[0] * inv;
    float var  = sm[256] * inv - mean * mean;
    float sc = gamma[o] * rsqrtf(var + 1e-5f);
    float sh = beta[o] - mean * sc;
    scsh[o]      = sc;
    scsh[64 + o] = sh;
  }
}

// --- P3: in-place BN-apply + ReLU, float4 ----------------------------------
__global__ void bn_relu_kernel(float4* __restrict__ out, const float* __restrict__ scsh) {
  int i = blockIdx.x * blockDim.x + threadIdx.x;
  const int total = 7680000;        // 30.72M / 4 ; 7500%4==0 so o uniform per f4
  int stride = gridDim.x * blockDim.x;
  for (; i < total; i += stride) {
    int o = (i / 1875) & 63;
    float sc = scsh[o], sh = scsh[64 + o];
    float4 v = out[i];
    v.x = fmaxf(fmaf(v.x, sc, sh), 0.f);
    v.y = fmaxf(fmaf(v.y, sc, sh), 0.f);
    v.z = fmaxf(fmaf(v.z, sc, sh), 0.f);
    v.w = fmaxf(fmaf(v.w, sc, sh), 0.f);
    out[i] = v;
  }
}

// ---------------------------------------------------------------------------
extern "C" void kernel_launch(void* const* d_in, const int* in_sizes, int n_in,
                              void* d_out, int out_size, void* d_ws, size_t ws_size,
                              hipStream_t stream) {
  const float* x     = (const float*)d_in[0];
  const float* W     = (const float*)d_in[1];
  // d_in[2] = b : cancels under batch-norm, unused.
  const float* gamma = (const float*)d_in[3];
  const float* beta  = (const float*)d_in[4];
  float* out = (float*)d_out;

  char* ws = (char*)d_ws;
  s16x8* Wg       = (s16x8*)ws;                       // 204,800 B
  float* partials = (float*)(ws + 204800);            // 1920*128*4 = 983,040 B
  float* scsh     = (float*)(ws + 204800 + 983040);   // 512 B

  pack_w_kernel<<<dim3(50), dim3(256), 0, stream>>>(W, Wg);
  tap_mm_kernel<<<dim3(NBR_, 64), dim3(NTHR_), 0, stream>>>(x, Wg, out, partials);
  finalize_kernel<<<dim3(64), dim3(256), 0, stream>>>(partials, gamma, beta, scsh);
  bn_relu_kernel<<<dim3(2048), dim3(256), 0, stream>>>((float4*)out, scsh);
}

// Round 19
// 183.359 us; speedup vs baseline: 1.0305x; 1.0305x over previous
//
#include <hip/hip_runtime.h>

// ---------------------------------------------------------------------------
// unit_gcn: out[n,o,t,v] = BN+ReLU of  sum_{s=0..24} Ws[s] @_c x[n,:,t,(v+s)%25]
//   Ws[0] = sum_i W[i,:,:,0];  Ws[s] = W[s-1,:,:,1]  (s>=1); bias cancels in BN.
// N=64, C=64, T=300, V=25, O=64.  x fp32 -> bf16 MFMA (16x16x32), fp32 accum.
// v16 (R19): R18 with DPP direction FIXED: row_shl:1 (0x101) pulls lane l+1's
// frag (LLVM AtomicOptimizer buildScan uses row_shr for lower-lane pulls ->
// row_shl = higher-lane pull). A-frags advance across shifts in-register;
// exec-masked LDS fixup only for l15==15 or base_row%25==24 lanes.
// Removes ~16/18 KB LDS traffic per wave-shift -> ceiling 27% -> ~46%.
// ---------------------------------------------------------------------------

typedef short  s16x8 __attribute__((ext_vector_type(8)));
typedef float  f32x4 __attribute__((ext_vector_type(4)));

#define NTHR_   256
#define RPB_    250         // rows per block (exactly 10 t x 25 v)
#define NBR_    30          // 7500 / 250
#define TS_     260         // epilogue transpose stride (f32)

__device__ __forceinline__ unsigned short f2bf(float f) {
  unsigned u = __builtin_bit_cast(unsigned, f);
  return (unsigned short)((u + 0x7FFFu + ((u >> 16) & 1u)) >> 16);
}

// pull-from-lane(l+1) within 16-lane DPP rows, pure VALU: row_shl:1 = 0x101.
// Lane 15 of each row gets 0 (bound_ctrl) — always covered by the fixup mask.
__device__ __forceinline__ s16x8 rot16(s16x8 v) {
  union { s16x8 h; int i[4]; } a, b;
  a.h = v;
#pragma unroll
  for (int j = 0; j < 4; ++j)
    b.i[j] = __builtin_amdgcn_update_dpp(0, a.i[j], 0x101, 0xf, 0xf, true);
  return b.h;
}

// --- P0: pack Ws into MFMA B-fragment layout (s-major: q = s*2 + chunk) ----
// Wg entry idx = ((s*2+chunk)*4 + ni)*64 + lane ; 8 bf16 per entry:
//   elem j = Ws[s][ o = ni*16 + (lane&15) ][ c = chunk*32 + (lane>>4)*8 + j ]
__global__ void pack_w_kernel(const float* __restrict__ W, s16x8* __restrict__ Wg) {
  int idx = blockIdx.x * 256 + threadIdx.x;
  if (idx >= 12800) return;
  int lane  = idx & 63;
  int ni    = (idx >> 6) & 3;
  int chunk = (idx >> 8) & 1;
  int s     = idx >> 9;
  int o     = (ni << 4) + (lane & 15);
  int cbase = (chunk << 5) + ((lane >> 4) << 3);
  s16x8 h;
#pragma unroll
  for (int j = 0; j < 8; ++j) {
    int c = cbase + j;
    float val;
    if (s == 0) {
      val = 0.f;
      for (int i = 0; i < 24; ++i) val += W[((i * 64 + o) * 64 + c) * 2];
    } else {
      val = W[(((s - 1) * 64 + o) * 64 + c) * 2 + 1];
    }
    h[j] = (short)f2bf(val);
  }
  Wg[idx] = h;
}

// advance row-tile J's shift state (period 25); aoc is byte offset into Ash
#define ADV(J) { bool w_ = (u[J] == 24); u[J] = w_ ? 0 : u[J] + 1; \
                 aoc[J] += w_ ? -384 : 16; }
// one MFMA
#define MM(RT, CT, AF, BF) \
  acc[RT][CT] = __builtin_amdgcn_mfma_f32_16x16x32_bf16(AF, BF, acc[RT][CT], 0, 0, 0);

// ---- FULL shift (all-lane LDS reads) — used only for shift 0 --------------
#define SHIFT_F(S_, BB)                                                        \
  {                                                                            \
    int sc_ = (S_) + 2; sc_ = (sc_ > 24) ? 24 : sc_;                           \
    const s16x8* ws_ = Wg + sc_ * 512;                                         \
    s16x8 Br0_ = ws_[tid], Br1_ = ws_[256 + tid];                              \
    const char* bq_ = Bsh + (BB) * 8192 + 4096 + (lane << 4);                  \
    __builtin_amdgcn_s_setprio(1);                                             \
    Aq0 = *(const s16x8*)(Ash + aoc[0] + 16384);                               \
    MM(0, 0, Ap0, Bp0) MM(0, 1, Ap0, Bp1)                                      \
    Bq0 = *(const s16x8*)(bq_);                                                \
    MM(0, 2, Ap0, Bp2) MM(0, 3, Ap0, Bp3)                                      \
    Aq1 = *(const s16x8*)(Ash + aoc[1] + 16384);                               \
    MM(1, 0, Ap1, Bp0) MM(1, 1, Ap1, Bp1)                                      \
    Bq1 = *(const s16x8*)(bq_ + 1024);                                         \
    MM(1, 2, Ap1, Bp2) MM(1, 3, Ap1, Bp3)                                      \
    Aq2 = *(const s16x8*)(Ash + aoc[2] + 16384);                               \
    MM(2, 0, Ap2, Bp0) MM(2, 1, Ap2, Bp1)                                      \
    Bq2 = *(const s16x8*)(bq_ + 2048);                                         \
    MM(2, 2, Ap2, Bp2) MM(2, 3, Ap2, Bp3)                                      \
    Aq3 = *(const s16x8*)(Ash + aoc[3] + 16384);                               \
    MM(3, 0, Ap3, Bp0) MM(3, 1, Ap3, Bp1)                                      \
    Bq3 = *(const s16x8*)(bq_ + 3072);                                         \
    MM(3, 2, Ap3, Bp2) MM(3, 3, Ap3, Bp3)                                      \
    __builtin_amdgcn_s_setprio(0);                                             \
    __syncthreads();                                                           \
    const char* bp_ = Bsh + (((BB) ^ 1) * 8192) + (lane << 4);                 \
    __builtin_amdgcn_s_setprio(1);                                             \
    ADV(0) Ap0 = *(const s16x8*)(Ash + aoc[0]);                                \
    MM(0, 0, Aq0, Bq0) MM(0, 1, Aq0, Bq1)                                      \
    Bp0 = *(const s16x8*)(bp_);                                                \
    MM(0, 2, Aq0, Bq2) MM(0, 3, Aq0, Bq3)                                      \
    ADV(1) Ap1 = *(const s16x8*)(Ash + aoc[1]);                                \
    MM(1, 0, Aq1, Bq0) MM(1, 1, Aq1, Bq1)                                      \
    Bp1 = *(const s16x8*)(bp_ + 1024);                                         \
    MM(1, 2, Aq1, Bq2) MM(1, 3, Aq1, Bq3)                                      \
    ADV(2) Ap2 = *(const s16x8*)(Ash + aoc[2]);                                \
    MM(2, 0, Aq2, Bq0) MM(2, 1, Aq2, Bq1)                                      \
    Bp2 = *(const s16x8*)(bp_ + 2048);                                         \
    MM(2, 2, Aq2, Bq2) MM(2, 3, Aq2, Bq3)                                      \
    ADV(3) Ap3 = *(const s16x8*)(Ash + aoc[3]);                                \
    MM(3, 0, Aq3, Bq0) MM(3, 1, Aq3, Bq1)                                      \
    Bp3 = *(const s16x8*)(bp_ + 3072);                                         \
    MM(3, 2, Aq3, Bq2) MM(3, 3, Aq3, Bq3)                                      \
    __builtin_amdgcn_s_setprio(0);                                             \
    *(s16x8*)(Bsh + (BB) * 8192 + (tid << 4)) = Br0_;                          \
    *(s16x8*)(Bsh + (BB) * 8192 + 4096 + (tid << 4)) = Br1_;                   \
  }

// ---- ROTATED shift: A-frags via DPP lane-rotation + masked fixup ----------
// PH_A: Aq(s) = rot(Aq(s-1)) [+fixup at aoc(s)+16384]; 16 MFMA on Ap x Bp.
// PH_B: ADV; Ap(s+1) = rot(Ap(s)) [+fixup at aoc(s+1)]; 16 MFMA on Aq x Bq.
#define SHIFT_R(S_, BB)                                                        \
  {                                                                            \
    int sc_ = (S_) + 2; sc_ = (sc_ > 24) ? 24 : sc_;                           \
    const s16x8* ws_ = Wg + sc_ * 512;                                         \
    s16x8 Br0_ = ws_[tid], Br1_ = ws_[256 + tid];                              \
    const char* bq_ = Bsh + (BB) * 8192 + 4096 + (lane << 4);                  \
    __builtin_amdgcn_s_setprio(1);                                             \
    Aq0 = rot16(Aq0); if (nf0) Aq0 = *(const s16x8*)(Ash + aoc[0] + 16384);    \
    MM(0, 0, Ap0, Bp0) MM(0, 1, Ap0, Bp1)                                      \
    Bq0 = *(const s16x8*)(bq_);                                                \
    MM(0, 2, Ap0, Bp2) MM(0, 3, Ap0, Bp3)                                      \
    Aq1 = rot16(Aq1); if (nf1) Aq1 = *(const s16x8*)(Ash + aoc[1] + 16384);    \
    MM(1, 0, Ap1, Bp0) MM(1, 1, Ap1, Bp1)                                      \
    Bq1 = *(const s16x8*)(bq_ + 1024);                                         \
    MM(1, 2, Ap1, Bp2) MM(1, 3, Ap1, Bp3)                                      \
    Aq2 = rot16(Aq2); if (nf2) Aq2 = *(const s16x8*)(Ash + aoc[2] + 16384);    \
    MM(2, 0, Ap2, Bp0) MM(2, 1, Ap2, Bp1)                                      \
    Bq2 = *(const s16x8*)(bq_ + 2048);                                         \
    MM(2, 2, Ap2, Bp2) MM(2, 3, Ap2, Bp3)                                      \
    Aq3 = rot16(Aq3); if (nf3) Aq3 = *(const s16x8*)(Ash + aoc[3] + 16384);    \
    MM(3, 0, Ap3, Bp0) MM(3, 1, Ap3, Bp1)                                      \
    Bq3 = *(const s16x8*)(bq_ + 3072);                                         \
    MM(3, 2, Ap3, Bp2) MM(3, 3, Ap3, Bp3)                                      \
    __builtin_amdgcn_s_setprio(0);                                             \
    __syncthreads();                                                           \
    const char* bp_ = Bsh + (((BB) ^ 1) * 8192) + (lane << 4);                 \
    __builtin_amdgcn_s_setprio(1);                                             \
    ADV(0) Ap0 = rot16(Ap0); if (nf0) Ap0 = *(const s16x8*)(Ash + aoc[0]);     \
    MM(0, 0, Aq0, Bq0) MM(0, 1, Aq0, Bq1)                                      \
    Bp0 = *(const s16x8*)(bp_);                                                \
    MM(0, 2, Aq0, Bq2) MM(0, 3, Aq0, Bq3)                                      \
    ADV(1) Ap1 = rot16(Ap1); if (nf1) Ap1 = *(const s16x8*)(Ash + aoc[1]);     \
    MM(1, 0, Aq1, Bq0) MM(1, 1, Aq1, Bq1)                                      \
    Bp1 = *(const s16x8*)(bp_ + 1024);                                         \
    MM(1, 2, Aq1, Bq2) MM(1, 3, Aq1, Bq3)                                      \
    ADV(2) Ap2 = rot16(Ap2); if (nf2) Ap2 = *(const s16x8*)(Ash + aoc[2]);     \
    MM(2, 0, Aq2, Bq0) MM(2, 1, Aq2, Bq1)                                      \
    Bp2 = *(const s16x8*)(bp_ + 2048);                                         \
    MM(2, 2, Aq2, Bq2) MM(2, 3, Aq2, Bq3)                                      \
    ADV(3) Ap3 = rot16(Ap3); if (nf3) Ap3 = *(const s16x8*)(Ash + aoc[3]);     \
    MM(3, 0, Aq3, Bq0) MM(3, 1, Aq3, Bq1)                                      \
    Bp3 = *(const s16x8*)(bp_ + 3072);                                         \
    MM(3, 2, Aq3, Bq2) MM(3, 3, Aq3, Bq3)                                      \
    __builtin_amdgcn_s_setprio(0);                                             \
    *(s16x8*)(Bsh + (BB) * 8192 + (tid << 4)) = Br0_;                          \
    *(s16x8*)(Bsh + (BB) * 8192 + 4096 + (tid << 4)) = Br1_;                   \
  }

// --- P1: main tap-GEMM -----------------------------------------------------
// grid (br=30, n=64), 256 thr = 4 waves; wave owns 64 rows x 64 o.
// A_T[slot 0..7][row 0..255] 16B frags; frag(row,ch) addr = (ch*4+lk)*4096
// + row*16. LDS = Ash 32K + Bsh 16K = 48K; red2 aliases Bsh post-K-loop.
__global__ __launch_bounds__(NTHR_) void tap_mm_kernel(
    const float* __restrict__ x, const s16x8* __restrict__ Wg,
    float* __restrict__ out, float* __restrict__ partials) {
  __shared__ __align__(16) char Ash[32768];   // A_T 8x256x16B; epi T[16][260]
  __shared__ __align__(16) char Bsh[16384];   // B dbuf 2x8KB; later red2[512]
  float* red2 = (float*)Bsh;
  int br = blockIdx.x, n = blockIdx.y;
  int r0 = br * RPB_;                 // 25-aligned
  const float* xn = x + n * 480000 + r0;
  int tid = threadIdx.x;
  int wid = tid >> 6, lane = tid & 63;
  int l15 = lane & 15, lk = lane >> 4;

  // ---- B prologue: shifts 0 and 1 -> regs (L2-hot)
  s16x8 p0 = Wg[tid], p1 = Wg[256 + tid], p2 = Wg[512 + tid], p3 = Wg[768 + tid];

  // ---- stage A_T: iteration it = slot; row = tid (250..255 zero pad)
#pragma unroll 2
  for (int it = 0; it < 8; ++it) {
    bool vld = tid < RPB_;
    s16x8 h;
#pragma unroll
    for (int j = 0; j < 8; ++j) {
      float f = vld ? xn[((it << 3) + j) * 7500 + tid] : 0.f;
      h[j] = (short)f2bf(f);
    }
    *(s16x8*)(Ash + (it << 12) + (tid << 4)) = h;
  }
  // B(0) -> Bsh[0], B(1) -> Bsh[1]
  *(s16x8*)(Bsh + (tid << 4))         = p0;
  *(s16x8*)(Bsh + 4096 + (tid << 4))  = p1;
  *(s16x8*)(Bsh + 8192 + (tid << 4))  = p2;
  *(s16x8*)(Bsh + 12288 + (tid << 4)) = p3;

  // ---- per-lane A row state: aoc = lk*4096 + srow*16 (ch0 byte offset)
  int u[4], aoc[4];
#pragma unroll
  for (int rt = 0; rt < 4; ++rt) {
    int srow = (wid << 6) + (rt << 4) + l15;     // local slab row (A-side)
    u[rt]   = srow % 25;                         // r0 is 25-aligned
    aoc[rt] = (lk << 12) + (srow << 4);
  }
  // static fixup masks (shift-independent, in lane space): a lane cannot take
  // its +1 neighbor's frag iff l15==15 (DPP row edge) or base_row%25==24
  // (neighbor is in the next 25-row t-window)
  bool nf0 = (l15 == 15) || (((wid << 6) + 0 * 16 + l15) % 25 == 24);
  bool nf1 = (l15 == 15) || (((wid << 6) + 1 * 16 + l15) % 25 == 24);
  bool nf2 = (l15 == 15) || (((wid << 6) + 2 * 16 + l15) % 25 == 24);
  bool nf3 = (l15 == 15) || (((wid << 6) + 3 * 16 + l15) % 25 == 24);

  f32x4 acc[4][4];
#pragma unroll
  for (int rt = 0; rt < 4; ++rt)
#pragma unroll
    for (int ct = 0; ct < 4; ++ct) acc[rt][ct] = (f32x4){0.f, 0.f, 0.f, 0.f};

  __syncthreads();

  // ---- preload ch0 frags of shift 0
  s16x8 Ap0 = *(const s16x8*)(Ash + aoc[0]);
  s16x8 Ap1 = *(const s16x8*)(Ash + aoc[1]);
  s16x8 Ap2 = *(const s16x8*)(Ash + aoc[2]);
  s16x8 Ap3 = *(const s16x8*)(Ash + aoc[3]);
  const char* b0_ = Bsh + (lane << 4);
  s16x8 Bp0 = *(const s16x8*)(b0_);
  s16x8 Bp1 = *(const s16x8*)(b0_ + 1024);
  s16x8 Bp2 = *(const s16x8*)(b0_ + 2048);
  s16x8 Bp3 = *(const s16x8*)(b0_ + 3072);
  s16x8 Aq0, Aq1, Aq2, Aq3, Bq0, Bq1, Bq2, Bq3;

  // ---- shift 0 full, then 24 rotated shifts (buffer parity = s&1)
  SHIFT_F(0, 0)
  for (int k = 0; k < 11; ++k) {
    SHIFT_R(2 * k + 1, 1)
    SHIFT_R(2 * k + 2, 0)
  }
  SHIFT_R(23, 1)
  SHIFT_R(24, 0)

  __syncthreads();   // all waves done with Bsh B-frags -> safe to alias red2

  // ---- per-channel sum/sumsq from registers (rows < 250 only)
  float s1v[4] = {0.f, 0.f, 0.f, 0.f}, s2v[4] = {0.f, 0.f, 0.f, 0.f};
#pragma unroll
  for (int rt = 0; rt < 4; ++rt) {
#pragma unroll
    for (int qq = 0; qq < 4; ++qq) {
      int rloc = (wid << 6) + (rt << 4) + (lk << 2) + qq;  // C/D row
      if (rloc < RPB_) {
#pragma unroll
        for (int ct = 0; ct < 4; ++ct) {
          float val = acc[rt][ct][qq];
          s1v[ct] += val;
          s2v[ct] += val * val;
        }
      }
    }
  }
#pragma unroll
  for (int ct = 0; ct < 4; ++ct) {
    float a = s1v[ct], b = s2v[ct];
    a += __shfl_xor(a, 16); a += __shfl_xor(a, 32);
    b += __shfl_xor(b, 16); b += __shfl_xor(b, 32);
    if (lane < 16) {
      int base = ((((wid << 2) + ct) << 4) + l15) * 2;
      red2[base]     = a;
      red2[base + 1] = b;
    }
  }

  // ---- epilogue: 4 o-quarters via LDS transpose, coalesced float2 stores
  float* T = (float*)Ash;
  float* outb = out + n * 480000 + r0;     // + o*7500 + row
#pragma unroll
  for (int qt = 0; qt < 4; ++qt) {
    __syncthreads();   // qt=0: K-loop Ash reads + red2 writes done; else T reads
#pragma unroll
    for (int rt = 0; rt < 4; ++rt) {
      int row0 = (wid << 6) + (rt << 4) + (lk << 2);
      *(f32x4*)&T[l15 * TS_ + row0] = acc[rt][qt];
    }
    __syncthreads();
    if (qt == 0 && tid < 128) {   // deterministic partial reduction
      int o = tid >> 1, m = tid & 1;
      int ct = o >> 4, ol = o & 15;
      float sres = 0.f;
#pragma unroll
      for (int w = 0; w < 4; ++w)
        sres += red2[((((w << 2) + ct) << 4) + ol) * 2 + m];
      int bl = n * NBR_ + br;
      partials[bl * 128 + m * 64 + o] = sres;
    }
    // stores: 16 o x 125 float2 rows (250 rows, 8B aligned for any br)
#pragma unroll
    for (int it = 0; it < 8; ++it) {
      int idx = tid + it * NTHR_;
      if (idx < 2000) {
        int ol = idx / 125, r2 = idx - ol * 125;
        *(float2*)&outb[((qt << 4) + ol) * 7500 + (r2 << 1)] =
            *(float2*)&T[ol * TS_ + (r2 << 1)];
      }
    }
  }
}

// --- P2: reduce per-block partials -> per-channel scale/shift --------------
__global__ void finalize_kernel(const float* __restrict__ part,
                                const float* __restrict__ gamma,
                                const float* __restrict__ beta,
                                float* __restrict__ scsh) {
  __shared__ float sm[512];
  int o = blockIdx.x;            // 64 blocks, one channel each
  int tid = threadIdx.x;         // 256 threads
  float s1 = 0.f, s2 = 0.f;
  for (int b = tid; b < 64 * NBR_; b += 256) {
    s1 += part[b * 128 + o];
    s2 += part[b * 128 + 64 + o];
  }
  sm[tid] = s1; sm[256 + tid] = s2;
  __syncthreads();
  for (int st = 128; st >= 1; st >>= 1) {
    if (tid < st) { sm[tid] += sm[tid + st]; sm[256 + tid] += sm[256 + tid + st]; }
    __syncthreads();
  }
  if (tid == 0) {
    const float inv = 1.0f / 480000.0f;
    float mean = sm[0] * inv;
    float var  = sm[256] * inv - mean * mean;
    float sc = gamma[o] * rsqrtf(var + 1e-5f);
    float sh = beta[o] - mean * sc;
    scsh[o]      = sc;
    scsh[64 + o] = sh;
  }
}

// --- P3: in-place BN-apply + ReLU, float4 ----------------------------------
__global__ void bn_relu_kernel(float4* __restrict__ out, const float* __restrict__ scsh) {
  int i = blockIdx.x * blockDim.x + threadIdx.x;
  const int total = 7680000;        // 30.72M / 4 ; 7500%4==0 so o uniform per f4
  int stride = gridDim.x * blockDim.x;
  for (; i < total; i += stride) {
    int o = (i / 1875) & 63;
    float sc = scsh[o], sh = scsh[64 + o];
    float4 v = out[i];
    v.x = fmaxf(fmaf(v.x, sc, sh), 0.f);
    v.y = fmaxf(fmaf(v.y, sc, sh), 0.f);
    v.z = fmaxf(fmaf(v.z, sc, sh), 0.f);
    v.w = fmaxf(fmaf(v.w, sc, sh), 0.f);
    out[i] = v;
  }
}

// ---------------------------------------------------------------------------
extern "C" void kernel_launch(void* const* d_in, const int* in_sizes, int n_in,
                              void* d_out, int out_size, void* d_ws, size_t ws_size,
                              hipStream_t stream) {
  const float* x     = (const float*)d_in[0];
  const float* W     = (const float*)d_in[1];
  // d_in[2] = b : cancels under batch-norm, unused.
  const float* gamma = (const float*)d_in[3];
  const float* beta  = (const float*)d_in[4];
  float* out = (float*)d_out;

  char* ws = (char*)d_ws;
  s16x8* Wg       = (s16x8*)ws;                       // 204,800 B
  float* partials = (float*)(ws + 204800);            // 1920*128*4 = 983,040 B
  float* scsh     = (float*)(ws + 204800 + 983040);   // 512 B

  pack_w_kernel<<<dim3(50), dim3(256), 0, stream>>>(W, Wg);
  tap_mm_kernel<<<dim3(NBR_, 64), dim3(NTHR_), 0, stream>>>(x, Wg, out, partials);
  finalize_kernel<<<dim3(64), dim3(256), 0, stream>>>(partials, gamma, beta, scsh);
  bn_relu_kernel<<<dim3(2048), dim3(256), 0, stream>>>((float4*)out, scsh);
}

// Round 20
// 172.144 us; speedup vs baseline: 1.0977x; 1.0652x over previous
//
#include <hip/hip_runtime.h>

// ---------------------------------------------------------------------------
// unit_gcn: out[n,o,t,v] = BN+ReLU of  sum_{s=0..24} Ws[s] @_c x[n,:,t,(v+s)%25]
//   Ws[0] = sum_i W[i,:,:,0];  Ws[s] = W[s-1,:,:,1]  (s>=1); bias cancels in BN.
// N=64, C=64, T=300, V=25, O=64.  x fp32 -> bf16 MFMA (16x16x32), fp32 accum.
// v17 (R20): R16 verbatim + __launch_bounds__(256, 3). Isolated residency
// experiment: LDS (48KB) and regs (156 unified) permit 3 blocks/CU but only
// 2 are resident across R12-R19; the declared-max-waves metadata is the one
// untested blocker. Cross-round law: util ~= 8-9 pts per wave/SIMD.
// ---------------------------------------------------------------------------

typedef short  s16x8 __attribute__((ext_vector_type(8)));
typedef float  f32x4 __attribute__((ext_vector_type(4)));

#define NTHR_   256
#define RPB_    250         // rows per block (exactly 10 t x 25 v)
#define NBR_    30          // 7500 / 250
#define TS_     260         // epilogue transpose stride (f32)

__device__ __forceinline__ unsigned short f2bf(float f) {
  unsigned u = __builtin_bit_cast(unsigned, f);
  return (unsigned short)((u + 0x7FFFu + ((u >> 16) & 1u)) >> 16);
}

// --- P0: pack Ws into MFMA B-fragment layout (s-major: q = s*2 + chunk) ----
// Wg entry idx = ((s*2+chunk)*4 + ni)*64 + lane ; 8 bf16 per entry:
//   elem j = Ws[s][ o = ni*16 + (lane&15) ][ c = chunk*32 + (lane>>4)*8 + j ]
__global__ void pack_w_kernel(const float* __restrict__ W, s16x8* __restrict__ Wg) {
  int idx = blockIdx.x * 256 + threadIdx.x;
  if (idx >= 12800) return;
  int lane  = idx & 63;
  int ni    = (idx >> 6) & 3;
  int chunk = (idx >> 8) & 1;
  int s     = idx >> 9;
  int o     = (ni << 4) + (lane & 15);
  int cbase = (chunk << 5) + ((lane >> 4) << 3);
  s16x8 h;
#pragma unroll
  for (int j = 0; j < 8; ++j) {
    int c = cbase + j;
    float val;
    if (s == 0) {
      val = 0.f;
      for (int i = 0; i < 24; ++i) val += W[((i * 64 + o) * 64 + c) * 2];
    } else {
      val = W[(((s - 1) * 64 + o) * 64 + c) * 2 + 1];
    }
    h[j] = (short)f2bf(val);
  }
  Wg[idx] = h;
}

// advance row-tile J's shift state (period 25); aoc is byte offset into Ash
#define ADV(J) { bool w_ = (u[J] == 24); u[J] = w_ ? 0 : u[J] + 1; \
                 aoc[J] += w_ ? -384 : 16; }
// one MFMA
#define MM(RT, CT, AF, BF) \
  acc[RT][CT] = __builtin_amdgcn_mfma_f32_16x16x32_bf16(AF, BF, acc[RT][CT], 0, 0, 0);

// One shift s (buffer BB = s&1). Entry: Ap0-3/Bp0-3 = ch0 frags of s.
// PH_A: 16 MFMA (ch0) + read Aq/Bq (ch1 of s; A at +16384, B from Bsh[BB]).
// barrier. PH_B: 16 MFMA (ch1) + read Ap/Bp (ch0 of s+1; B from Bsh[BB^1]).
// Then write B(s+2) (reg-staged at shift top) into Bsh[BB].
#define SHIFT(S_, BB)                                                          \
  {                                                                            \
    int sc_ = (S_) + 2; sc_ = (sc_ > 24) ? 24 : sc_;                           \
    const s16x8* ws_ = Wg + sc_ * 512;                                         \
    s16x8 Br0_ = ws_[tid], Br1_ = ws_[256 + tid];                              \
    const char* bq_ = Bsh + (BB) * 8192 + 4096 + (lane << 4);                  \
    __builtin_amdgcn_s_setprio(1);                                             \
    Aq0 = *(const s16x8*)(Ash + aoc[0] + 16384);                               \
    MM(0, 0, Ap0, Bp0) MM(0, 1, Ap0, Bp1)                                      \
    Bq0 = *(const s16x8*)(bq_);                                                \
    MM(0, 2, Ap0, Bp2) MM(0, 3, Ap0, Bp3)                                      \
    Aq1 = *(const s16x8*)(Ash + aoc[1] + 16384);                               \
    MM(1, 0, Ap1, Bp0) MM(1, 1, Ap1, Bp1)                                      \
    Bq1 = *(const s16x8*)(bq_ + 1024);                                         \
    MM(1, 2, Ap1, Bp2) MM(1, 3, Ap1, Bp3)                                      \
    Aq2 = *(const s16x8*)(Ash + aoc[2] + 16384);                               \
    MM(2, 0, Ap2, Bp0) MM(2, 1, Ap2, Bp1)                                      \
    Bq2 = *(const s16x8*)(bq_ + 2048);                                         \
    MM(2, 2, Ap2, Bp2) MM(2, 3, Ap2, Bp3)                                      \
    Aq3 = *(const s16x8*)(Ash + aoc[3] + 16384);                               \
    MM(3, 0, Ap3, Bp0) MM(3, 1, Ap3, Bp1)                                      \
    Bq3 = *(const s16x8*)(bq_ + 3072);                                         \
    MM(3, 2, Ap3, Bp2) MM(3, 3, Ap3, Bp3)                                      \
    __builtin_amdgcn_s_setprio(0);                                             \
    __syncthreads();                                                           \
    const char* bp_ = Bsh + (((BB) ^ 1) * 8192) + (lane << 4);                 \
    __builtin_amdgcn_s_setprio(1);                                             \
    ADV(0) Ap0 = *(const s16x8*)(Ash + aoc[0]);                                \
    MM(0, 0, Aq0, Bq0) MM(0, 1, Aq0, Bq1)                                      \
    Bp0 = *(const s16x8*)(bp_);                                                \
    MM(0, 2, Aq0, Bq2) MM(0, 3, Aq0, Bq3)                                      \
    ADV(1) Ap1 = *(const s16x8*)(Ash + aoc[1]);                                \
    MM(1, 0, Aq1, Bq0) MM(1, 1, Aq1, Bq1)                                      \
    Bp1 = *(const s16x8*)(bp_ + 1024);                                         \
    MM(1, 2, Aq1, Bq2) MM(1, 3, Aq1, Bq3)                                      \
    ADV(2) Ap2 = *(const s16x8*)(Ash + aoc[2]);                                \
    MM(2, 0, Aq2, Bq0) MM(2, 1, Aq2, Bq1)                                      \
    Bp2 = *(const s16x8*)(bp_ + 2048);                                         \
    MM(2, 2, Aq2, Bq2) MM(2, 3, Aq2, Bq3)                                      \
    ADV(3) Ap3 = *(const s16x8*)(Ash + aoc[3]);                                \
    MM(3, 0, Aq3, Bq0) MM(3, 1, Aq3, Bq1)                                      \
    Bp3 = *(const s16x8*)(bp_ + 3072);                                         \
    MM(3, 2, Aq3, Bq2) MM(3, 3, Aq3, Bq3)                                      \
    __builtin_amdgcn_s_setprio(0);                                             \
    *(s16x8*)(Bsh + (BB) * 8192 + (tid << 4)) = Br0_;                          \
    *(s16x8*)(Bsh + (BB) * 8192 + 4096 + (tid << 4)) = Br1_;                   \
  }

// --- P1: main tap-GEMM -----------------------------------------------------
// grid (br=30, n=64), 256 thr = 4 waves; wave owns 64 rows x 64 o.
// A-slab TRANSPOSED: A_T[slot 0..7][row 0..255] 16B frags; slot = c-group,
// frag(row, ch) for lane: addr = (ch*4 + lk)*4096 + row*16.
// LDS = Ash 32K + Bsh 16K = 48K; red2 ALIASES Bsh (dead post-K-loop).
__global__ __launch_bounds__(NTHR_, 3) void tap_mm_kernel(
    const float* __restrict__ x, const s16x8* __restrict__ Wg,
    float* __restrict__ out, float* __restrict__ partials) {
  __shared__ __align__(16) char Ash[32768];   // A_T 8x256x16B; epi T[16][260]
  __shared__ __align__(16) char Bsh[16384];   // B dbuf 2x8KB; later red2[512]
  float* red2 = (float*)Bsh;
  int br = blockIdx.x, n = blockIdx.y;
  int r0 = br * RPB_;                 // 25-aligned
  const float* xn = x + n * 480000 + r0;
  int tid = threadIdx.x;
  int wid = tid >> 6, lane = tid & 63;
  int l15 = lane & 15, lk = lane >> 4;

  // ---- B prologue: shifts 0 and 1 -> regs (L2-hot)
  s16x8 p0 = Wg[tid], p1 = Wg[256 + tid], p2 = Wg[512 + tid], p3 = Wg[768 + tid];

  // ---- stage A_T: iteration it = slot; row = tid (250..255 zero pad)
#pragma unroll 2
  for (int it = 0; it < 8; ++it) {
    bool vld = tid < RPB_;
    s16x8 h;
#pragma unroll
    for (int j = 0; j < 8; ++j) {
      float f = vld ? xn[((it << 3) + j) * 7500 + tid] : 0.f;
      h[j] = (short)f2bf(f);
    }
    *(s16x8*)(Ash + (it << 12) + (tid << 4)) = h;
  }
  // B(0) -> Bsh[0], B(1) -> Bsh[1]
  *(s16x8*)(Bsh + (tid << 4))         = p0;
  *(s16x8*)(Bsh + 4096 + (tid << 4))  = p1;
  *(s16x8*)(Bsh + 8192 + (tid << 4))  = p2;
  *(s16x8*)(Bsh + 12288 + (tid << 4)) = p3;

  // ---- per-lane A row state: aoc = lk*4096 + srow*16 (ch0 byte offset)
  int u[4], aoc[4];
#pragma unroll
  for (int rt = 0; rt < 4; ++rt) {
    int srow = (wid << 6) + (rt << 4) + l15;     // local slab row (A-side)
    u[rt]   = srow % 25;                         // r0 is 25-aligned
    aoc[rt] = (lk << 12) + (srow << 4);
  }
  f32x4 acc[4][4];
#pragma unroll
  for (int rt = 0; rt < 4; ++rt)
#pragma unroll
    for (int ct = 0; ct < 4; ++ct) acc[rt][ct] = (f32x4){0.f, 0.f, 0.f, 0.f};

  __syncthreads();

  // ---- preload ch0 frags of shift 0
  s16x8 Ap0 = *(const s16x8*)(Ash + aoc[0]);
  s16x8 Ap1 = *(const s16x8*)(Ash + aoc[1]);
  s16x8 Ap2 = *(const s16x8*)(Ash + aoc[2]);
  s16x8 Ap3 = *(const s16x8*)(Ash + aoc[3]);
  const char* b0_ = Bsh + (lane << 4);
  s16x8 Bp0 = *(const s16x8*)(b0_);
  s16x8 Bp1 = *(const s16x8*)(b0_ + 1024);
  s16x8 Bp2 = *(const s16x8*)(b0_ + 2048);
  s16x8 Bp3 = *(const s16x8*)(b0_ + 3072);
  s16x8 Aq0, Aq1, Aq2, Aq3, Bq0, Bq1, Bq2, Bq3;

  // ---- 25 shifts (buffer parity = s&1)
  for (int k = 0; k < 12; ++k) {
    SHIFT(2 * k, 0)
    SHIFT(2 * k + 1, 1)
  }
  SHIFT(24, 0)

  __syncthreads();   // all waves done with Bsh B-frags -> safe to alias red2

  // ---- per-channel sum/sumsq from registers (rows < 250 only)
  float s1v[4] = {0.f, 0.f, 0.f, 0.f}, s2v[4] = {0.f, 0.f, 0.f, 0.f};
#pragma unroll
  for (int rt = 0; rt < 4; ++rt) {
#pragma unroll
    for (int qq = 0; qq < 4; ++qq) {
      int rloc = (wid << 6) + (rt << 4) + (lk << 2) + qq;  // C/D row
      if (rloc < RPB_) {
#pragma unroll
        for (int ct = 0; ct < 4; ++ct) {
          float val = acc[rt][ct][qq];
          s1v[ct] += val;
          s2v[ct] += val * val;
        }
      }
    }
  }
#pragma unroll
  for (int ct = 0; ct < 4; ++ct) {
    float a = s1v[ct], b = s2v[ct];
    a += __shfl_xor(a, 16); a += __shfl_xor(a, 32);
    b += __shfl_xor(b, 16); b += __shfl_xor(b, 32);
    if (lane < 16) {
      int base = ((((wid << 2) + ct) << 4) + l15) * 2;
      red2[base]     = a;
      red2[base + 1] = b;
    }
  }

  // ---- epilogue: 4 o-quarters via LDS transpose, coalesced float2 stores
  float* T = (float*)Ash;
  float* outb = out + n * 480000 + r0;     // + o*7500 + row
#pragma unroll
  for (int qt = 0; qt < 4; ++qt) {
    __syncthreads();   // qt=0: K-loop Ash reads + red2 writes done; else T reads
#pragma unroll
    for (int rt = 0; rt < 4; ++rt) {
      int row0 = (wid << 6) + (rt << 4) + (lk << 2);
      *(f32x4*)&T[l15 * TS_ + row0] = acc[rt][qt];
    }
    __syncthreads();
    if (qt == 0 && tid < 128) {   // deterministic partial reduction
      int o = tid >> 1, m = tid & 1;
      int ct = o >> 4, ol = o & 15;
      float sres = 0.f;
#pragma unroll
      for (int w = 0; w < 4; ++w)
        sres += red2[((((w << 2) + ct) << 4) + ol) * 2 + m];
      int bl = n * NBR_ + br;
      partials[bl * 128 + m * 64 + o] = sres;
    }
    // stores: 16 o x 125 float2 rows (250 rows, 8B aligned for any br)
#pragma unroll
    for (int it = 0; it < 8; ++it) {
      int idx = tid + it * NTHR_;
      if (idx < 2000) {
        int ol = idx / 125, r2 = idx - ol * 125;
        *(float2*)&outb[((qt << 4) + ol) * 7500 + (r2 << 1)] =
            *(float2*)&T[ol * TS_ + (r2 << 1)];
      }
    }
  }
}

// --- P2: reduce per-block partials -> per-channel scale/shift --------------
__global__ void finalize_kernel(const float* __restrict__ part,
                                const float* __restrict__ gamma,
                                const float* __restrict__ beta,
                                float* __restrict__ scsh) {
  __shared__ float sm[512];
  int o = blockIdx.x;            // 64 blocks, one channel each
  int tid = threadIdx.x;         // 256 threads
  float s1 = 0.f, s2 = 0.f;
  for (int b = tid; b < 64 * NBR_; b += 256) {
    s1 += part[b * 128 + o];
    s2 += part[b * 128 + 64 + o];
  }
  sm[tid] = s1; sm[256 + tid] = s2;
  __syncthreads();
  for (int st = 128; st >= 1; st >>= 1) {
    if (tid < st) { sm[tid] += sm[tid + st]; sm[256 + tid] += sm[256 + tid + st]; }
    __syncthreads();
  }
  if (tid == 0) {
    const float inv = 1.0f / 480000.0f;
    float mean = sm[0] * inv;
    float var  = sm[256] * inv - mean * mean;
    float sc = gamma[o] * rsqrtf(var + 1e-5f);
    float sh = beta[o] - mean * sc;
    scsh[o]      = sc;
    scsh[64 + o] = sh;
  }
}

// --- P3: in-place BN-apply + ReLU, float4 ----------------------------------
__global__ void bn_relu_kernel(float4* __restrict__ out, const float* __restrict__ scsh) {
  int i = blockIdx.x * blockDim.x + threadIdx.x;
  const int total = 7680000;        // 30.72M / 4 ; 7500%4==0 so o uniform per f4
  int stride = gridDim.x * blockDim.x;
  for (; i < total; i += stride) {
    int o = (i / 1875) & 63;
    float sc = scsh[o], sh = scsh[64 + o];
    float4 v = out[i];
    v.x = fmaxf(fmaf(v.x, sc, sh), 0.f);
    v.y = fmaxf(fmaf(v.y, sc, sh), 0.f);
    v.z = fmaxf(fmaf(v.z, sc, sh), 0.f);
    v.w = fmaxf(fmaf(v.w, sc, sh), 0.f);
    out[i] = v;
  }
}

// ---------------------------------------------------------------------------
extern "C" void kernel_launch(void* const* d_in, const int* in_sizes, int n_in,
                              void* d_out, int out_size, void* d_ws, size_t ws_size,
                              hipStream_t stream) {
  const float* x     = (const float*)d_in[0];
  const float* W     = (const float*)d_in[1];
  // d_in[2] = b : cancels under batch-norm, unused.
  const float* gamma = (const float*)d_in[3];
  const float* beta  = (const float*)d_in[4];
  float* out = (float*)d_out;

  char* ws = (char*)d_ws;
  s16x8* Wg       = (s16x8*)ws;                       // 204,800 B
  float* partials = (float*)(ws + 204800);            // 1920*128*4 = 983,040 B
  float* scsh     = (float*)(ws + 204800 + 983040);   // 512 B

  pack_w_kernel<<<dim3(50), dim3(256), 0, stream>>>(W, Wg);
  tap_mm_kernel<<<dim3(NBR_, 64), dim3(NTHR_), 0, stream>>>(x, Wg, out, partials);
  finalize_kernel<<<dim3(64), dim3(256), 0, stream>>>(partials, gamma, beta, scsh);
  bn_relu_kernel<<<dim3(2048), dim3(256), 0, stream>>>((float4*)out, scsh);
}